// Round 21
// baseline (208.794 us; speedup 1.0000x reference)
//
#include <hip/hip_runtime.h>

#define E   128
#define HD  32
#define NB  512
#define NN  65536
#define TT  (NB + NN)   // 66048 tokens: [0,NB) metal, [NB,TT) nodes
#define TE  ((size_t)TT * 128)

typedef __attribute__((ext_vector_type(8))) short short8;
typedef __attribute__((ext_vector_type(4))) float f32x4;

__device__ __forceinline__ const float* row_ptr(const float* base, const float* metal, int t) {
  return (t < NB) ? metal + (size_t)t * E : base + (size_t)(t - NB) * E;
}
__device__ __forceinline__ float* row_ptr_w(float* base, float* metal, int t) {
  return (t < NB) ? metal + (size_t)t * E : base + (size_t)(t - NB) * E;
}

__device__ __forceinline__ unsigned short f2bf_rne(float x) {
  unsigned u = __float_as_uint(x);
  return (unsigned short)((u + 0x7FFFu + ((u >> 16) & 1u)) >> 16);
}
__device__ __forceinline__ void split_bf(float x, unsigned short& h, unsigned short& l) {
  h = f2bf_rne(x);
  float hf = __uint_as_float(((unsigned)h) << 16);
  l = f2bf_rne(x - hf);
}

// Merged setup: blocks [0,256) compute start[]; blocks [256,640) split weights.
// Rows of W: [0,128)Wq | [128,256)Wk | [256,640)in_w | [640,768)out_w
__global__ void k_setup(const int* __restrict__ batch, int* __restrict__ start,
                        const float* __restrict__ Wq, const float* __restrict__ Wk,
                        const float* __restrict__ in_w, const float* __restrict__ out_w,
                        unsigned short* __restrict__ Wh, unsigned short* __restrict__ Wl) {
  int b = blockIdx.x;
  if (b < 256) {
    int i = b * 256 + threadIdx.x;
    int bi = batch[i];
    int bp = (i == 0) ? -1 : batch[i - 1];
    for (int g = bp + 1; g <= bi; ++g) start[g] = i;
    if (i == NN - 1)
      for (int g = bi + 1; g <= NB; ++g) start[g] = NN;
  } else {
    int idx = (b - 256) * 256 + threadIdx.x;
    int r = idx >> 7, c = idx & 127;
    float v;
    if (r < 128)      v = Wq[r * 128 + c];
    else if (r < 256) v = Wk[(r - 128) * 128 + c];
    else if (r < 640) v = in_w[(r - 256) * 128 + c];
    else              v = out_w[(r - 640) * 128 + c];
    unsigned short h, l;
    split_bf(v, h, l);
    Wh[idx] = h;
    Wl[idx] = l;
  }
}

// seq row of token t (inline everywhere; k_seqmap kernel eliminated):
//   metal g -> start[g]+g ; node i -> i + batch[i] + 1
__device__ __forceinline__ int seq_row(const int* __restrict__ start,
                                       const int* __restrict__ batch,
                                       bool isMetal, int t) {
  return isMetal ? (start[t] + t) : (t - NB + batch[t - NB] + 1);
}

// out = ctx@out_w^T + b. A = single-bf16 ctx (seq order) gathered via inline
// seq-row; W = SINGLE bf16 (round-19/20 proven numeric config). 1 MFMA per
// 16x16 tile. LDS 20480 B.
__global__ __launch_bounds__(256, 3)
void k_outproj(const unsigned short* __restrict__ Ch,
               const int* __restrict__ start, const int* __restrict__ batch,
               const unsigned short* __restrict__ Wh,
               const float* __restrict__ bias,
               float* __restrict__ Cx, float* __restrict__ Cm) {
  __shared__ char smem[20480];
  unsigned short (*AshH)[40] = (unsigned short (*)[40])smem;            // 10240 B
  unsigned short (*WldsH)[40] = (unsigned short (*)[40])(smem + 10240); // 10240 B

  const int tid = threadIdx.x;
  const int wave = tid >> 6;
  const int lane = tid & 63;
  const int lrow = lane & 15;
  const int q = lane >> 4;
  const int t0 = blockIdx.x * 128;
  const bool isMetal = (t0 < NB);   // block-uniform: t0 multiple of 128, NB=512

  f32x4 acc[2][8];
  #pragma unroll
  for (int mt = 0; mt < 2; ++mt)
    #pragma unroll
    for (int nt = 0; nt < 8; ++nt) acc[mt][nt] = (f32x4){0.f, 0.f, 0.f, 0.f};

  for (int ks = 0; ks < 4; ++ks) {
    __syncthreads();
    // A staging: 512 tasks, 2 per thread (row 0..127, seg 0..3)
    #pragma unroll
    for (int u = 0; u < 2; ++u) {
      int e = tid + u * 256;        // [0,512)
      int row = e >> 2, seg = e & 3;
      int trow = t0 + row;
      int s = seq_row(start, batch, isMetal, trow);
      size_t go = (size_t)s * 128 + ks * 32 + seg * 8;
      *(short8*)&AshH[row][seg * 8] = *(const short8*)(Ch + go);
    }
    // W hi slice: 512 tasks, 2 per thread
    #pragma unroll
    for (int u = 0; u < 2; ++u) {
      int e = tid + u * 256;        // [0,512)
      int j = e >> 2, seg = e & 3;
      *(short8*)&WldsH[j][seg * 8] = *(const short8*)(Wh + j * 128 + ks * 32 + seg * 8);
    }
    __syncthreads();

    short8 ah[2];
    #pragma unroll
    for (int mt = 0; mt < 2; ++mt) {
      int m = wave * 32 + mt * 16 + lrow;
      ah[mt] = *(const short8*)&AshH[m][q * 8];
    }

    #pragma unroll
    for (int nt = 0; nt < 8; ++nt) {
      int j = nt * 16 + lrow;
      short8 bh = *(const short8*)&WldsH[j][q * 8];
      #pragma unroll
      for (int mt = 0; mt < 2; ++mt)
        acc[mt][nt] = __builtin_amdgcn_mfma_f32_16x16x32_bf16(ah[mt], bh, acc[mt][nt], 0, 0, 0);
    }
  }

  #pragma unroll
  for (int mt = 0; mt < 2; ++mt) {
    #pragma unroll
    for (int reg = 0; reg < 4; ++reg) {
      int t = t0 + wave * 32 + mt * 16 + q * 4 + reg;
      float* cp = row_ptr_w(Cx, Cm, t);
      #pragma unroll
      for (int nt = 0; nt < 8; ++nt) {
        int j = nt * 16 + lrow;
        cp[j] = acc[mt][nt][reg] + bias[j];
      }
    }
  }
}

// Merged projection kernel: 3*516 blocks, group = blockIdx.x % 3.
//   group 0: x -> Hq=relu(x@Wq^T+bq) -> Q=(Hq@Wiq^T+b)*SCL2  (split-bf16 seq)
//   group 1: x -> Hk=relu(x@Wk^T+bk) -> K= Hk@Wik^T+b        (split-bf16 seq)
//   group 2: x -> V = x@Wiv^T+b                               (bf16 seq)
// UNIFORM inner loops for all groups; seq rows computed inline (no seqmap).
// Epilogues drain through per-wave LDS transpose tiles for short8 global stores.
__global__ __launch_bounds__(256, 2)
void k_mega(const float* __restrict__ x, const float* __restrict__ metal_x,
            const unsigned short* __restrict__ Wh, const unsigned short* __restrict__ Wl,
            const float* __restrict__ bq, const float* __restrict__ bk,
            const float* __restrict__ in_b, float scl2,
            unsigned short* __restrict__ Voh,
            unsigned short* __restrict__ Qsh, unsigned short* __restrict__ Qsl,
            unsigned short* __restrict__ Ksh, unsigned short* __restrict__ Ksl,
            const int* __restrict__ start, const int* __restrict__ batch) {
  __shared__ char smem[40960];
  // stage-1 overlay
  float (*Afl)[36] = (float (*)[36])smem;                                   // 18432 B
  unsigned short (*WldsH)[40] = (unsigned short (*)[40])(smem + 18432);     // 10240 B
  unsigned short (*WldsL)[40] = (unsigned short (*)[40])(smem + 28672);     // 10240 B
  // stage-2 overlay (separated from stage-1 by __syncthreads)
  unsigned short (*AshH)[40] = (unsigned short (*)[40])smem;
  unsigned short (*AshL)[40] = (unsigned short (*)[40])(smem + 10240);
  unsigned short (*W2ldsH)[40] = (unsigned short (*)[40])(smem + 20480);
  unsigned short (*W2ldsL)[40] = (unsigned short (*)[40])(smem + 30720);

  const int tid = threadIdx.x;
  const int wave = tid >> 6;
  const int lane = tid & 63;
  const int lrow = lane & 15;
  const int q = lane >> 4;
  const int group = (int)(blockIdx.x % 3);
  const int t0 = (int)(blockIdx.x / 3) * 128;
  const bool isMetal = (t0 < NB);   // block-uniform

  // per-wave epilogue transpose tiles (reuse smem after a barrier):
  unsigned short (*EldsH)[136] = (unsigned short (*)[136])(smem + wave * 8704);
  unsigned short (*EldsL)[136] = (unsigned short (*)[136])(smem + wave * 8704 + 4352);

  // stage-1 weight: g0 Wq (rows 0), g1 Wk (rows 128), g2 in_w V-proj (rows 512)
  const int w1o = (group == 0) ? 0 : (group == 1) ? 128 * 128 : 512 * 128;
  const unsigned short* W1h = Wh + w1o;
  const unsigned short* W1l = Wl + w1o;

  f32x4 acc1[2][8];
  #pragma unroll
  for (int mt = 0; mt < 2; ++mt)
    #pragma unroll
    for (int nt = 0; nt < 8; ++nt) acc1[mt][nt] = (f32x4){0.f, 0.f, 0.f, 0.f};

  // ---- stage 1: x tile -> acc1 ----
  for (int ks = 0; ks < 4; ++ks) {
    __syncthreads();
    #pragma unroll
    for (int u = 0; u < 4; ++u) {
      int e4 = tid + u * 256;
      int m = e4 >> 3, k4 = e4 & 7;
      const float* rp = row_ptr(x, metal_x, t0 + m);
      float4 v = ((const float4*)(rp + ks * 32))[k4];
      *(float4*)&Afl[m][k4 * 4] = v;
    }
    #pragma unroll
    for (int u = 0; u < 4; ++u) {
      int idx = tid + u * 256;
      int half = idx >> 9, rem = idx & 511;
      int j = rem >> 2, seg = rem & 3;
      const unsigned short* src = (half ? W1l : W1h) + j * 128 + ks * 32 + seg * 8;
      short8 v = *(const short8*)src;
      unsigned short* dst = (half ? &WldsL[j][seg * 8] : &WldsH[j][seg * 8]);
      *(short8*)dst = v;
    }
    __syncthreads();

    short8 ah[2], al[2];
    #pragma unroll
    for (int mt = 0; mt < 2; ++mt) {
      int m = wave * 32 + mt * 16 + lrow;
      float4 f0 = *(const float4*)&Afl[m][q * 8];
      float4 f1 = *(const float4*)&Afl[m][q * 8 + 4];
      unsigned short h, l;
      split_bf(f0.x, h, l); ah[mt][0] = (short)h; al[mt][0] = (short)l;
      split_bf(f0.y, h, l); ah[mt][1] = (short)h; al[mt][1] = (short)l;
      split_bf(f0.z, h, l); ah[mt][2] = (short)h; al[mt][2] = (short)l;
      split_bf(f0.w, h, l); ah[mt][3] = (short)h; al[mt][3] = (short)l;
      split_bf(f1.x, h, l); ah[mt][4] = (short)h; al[mt][4] = (short)l;
      split_bf(f1.y, h, l); ah[mt][5] = (short)h; al[mt][5] = (short)l;
      split_bf(f1.z, h, l); ah[mt][6] = (short)h; al[mt][6] = (short)l;
      split_bf(f1.w, h, l); ah[mt][7] = (short)h; al[mt][7] = (short)l;
    }

    #pragma unroll
    for (int nt = 0; nt < 8; ++nt) {
      int j = nt * 16 + lrow;
      short8 bh = *(const short8*)&WldsH[j][q * 8];
      short8 bl = *(const short8*)&WldsL[j][q * 8];
      #pragma unroll
      for (int mt = 0; mt < 2; ++mt) {
        acc1[mt][nt] = __builtin_amdgcn_mfma_f32_16x16x32_bf16(ah[mt], bh, acc1[mt][nt], 0, 0, 0);
        acc1[mt][nt] = __builtin_amdgcn_mfma_f32_16x16x32_bf16(al[mt], bh, acc1[mt][nt], 0, 0, 0);
        acc1[mt][nt] = __builtin_amdgcn_mfma_f32_16x16x32_bf16(ah[mt], bl, acc1[mt][nt], 0, 0, 0);
      }
    }
  }

  // ---- group 2: V epilogue (bf16 seq order, LDS-transposed wide stores) ----
  if (group == 2) {
    const float* bv = in_b + 2 * E;
    float bvv[8];
    #pragma unroll
    for (int nt = 0; nt < 8; ++nt) bvv[nt] = bv[nt * 16 + lrow];
    __syncthreads();   // all waves done with stage-1 LDS before Elds reuse
    #pragma unroll
    for (int mt = 0; mt < 2; ++mt) {
      #pragma unroll
      for (int reg = 0; reg < 4; ++reg)
        #pragma unroll
        for (int nt = 0; nt < 8; ++nt)
          EldsH[q * 4 + reg][nt * 16 + lrow] = f2bf_rne(acc1[mt][nt][reg] + bvv[nt]);
      #pragma unroll
      for (int u = 0; u < 4; ++u) {
        int task = lane + 64 * u;                 // 256: row=task>>4, seg=task&15
        int row16 = task >> 4, seg = task & 15;
        int t = t0 + wave * 32 + mt * 16 + row16;
        int s = seq_row(start, batch, isMetal, t);
        size_t ro = (size_t)s * 128 + seg * 8;
        *(short8*)(Voh + ro) = *(const short8*)&EldsH[row16][seg * 8];
      }
    }
    return;
  }

  // ---- groups 0/1: stage 2 ----
  const int w2o = (group == 0) ? 256 * 128 : 384 * 128;
  const unsigned short* W2h = Wh + w2o;
  const unsigned short* W2l = Wl + w2o;
  const float* b1 = (group == 0) ? bq : bk;
  const float* b2 = (group == 0) ? in_b : in_b + 128;
  const float postscale = (group == 0) ? scl2 : 1.f;
  unsigned short* Oh = (group == 0) ? Qsh : Ksh;
  unsigned short* Ol = (group == 0) ? Qsl : Ksl;

  f32x4 acc2[2][8];
  #pragma unroll
  for (int mt = 0; mt < 2; ++mt)
    #pragma unroll
    for (int nt = 0; nt < 8; ++nt) acc2[mt][nt] = (f32x4){0.f, 0.f, 0.f, 0.f};

  float b1v[8];
  #pragma unroll
  for (int nt = 0; nt < 8; ++nt) b1v[nt] = b1[nt * 16 + lrow];

  #pragma unroll
  for (int ks2 = 0; ks2 < 4; ++ks2) {
    __syncthreads();   // previous overlay reads done (incl. stage-1 last iter)
    #pragma unroll
    for (int u = 0; u < 4; ++u) {
      int idx = tid + u * 256;
      int half = idx >> 9, rem = idx & 511;
      int j = rem >> 2, seg = rem & 3;
      const unsigned short* src = (half ? W2l : W2h) + j * 128 + ks2 * 32 + seg * 8;
      short8 v = *(const short8*)src;
      unsigned short* dst = (half ? &W2ldsL[j][seg * 8] : &W2ldsH[j][seg * 8]);
      *(short8*)dst = v;
    }
    // H k-slice: registers (C/D layout) -> LDS A-slice (split hi/lo)
    #pragma unroll
    for (int mt = 0; mt < 2; ++mt) {
      #pragma unroll
      for (int n2 = 0; n2 < 2; ++n2) {
        const int nt = ks2 * 2 + n2;
        #pragma unroll
        for (int reg = 0; reg < 4; ++reg) {
          int row = wave * 32 + mt * 16 + q * 4 + reg;
          float v = fmaxf(acc1[mt][nt][reg] + b1v[nt], 0.f);
          unsigned short h, l;
          split_bf(v, h, l);
          AshH[row][n2 * 16 + lrow] = h;
          AshL[row][n2 * 16 + lrow] = l;
        }
      }
    }
    __syncthreads();

    short8 ah[2], al[2];
    #pragma unroll
    for (int mt = 0; mt < 2; ++mt) {
      int m = wave * 32 + mt * 16 + lrow;
      ah[mt] = *(const short8*)&AshH[m][q * 8];
      al[mt] = *(const short8*)&AshL[m][q * 8];
    }
    #pragma unroll
    for (int nt = 0; nt < 8; ++nt) {
      int j = nt * 16 + lrow;
      short8 bh = *(const short8*)&W2ldsH[j][q * 8];
      short8 bl = *(const short8*)&W2ldsL[j][q * 8];
      #pragma unroll
      for (int mt = 0; mt < 2; ++mt) {
        acc2[mt][nt] = __builtin_amdgcn_mfma_f32_16x16x32_bf16(ah[mt], bh, acc2[mt][nt], 0, 0, 0);
        acc2[mt][nt] = __builtin_amdgcn_mfma_f32_16x16x32_bf16(al[mt], bh, acc2[mt][nt], 0, 0, 0);
        acc2[mt][nt] = __builtin_amdgcn_mfma_f32_16x16x32_bf16(ah[mt], bl, acc2[mt][nt], 0, 0, 0);
      }
    }
  }

  // ---- O epilogue (split-bf16, seq order, LDS-transposed wide stores) ----
  {
    float b2v[8];
    #pragma unroll
    for (int nt = 0; nt < 8; ++nt) b2v[nt] = b2[nt * 16 + lrow];
    __syncthreads();   // all waves done with stage-2 LDS before Elds reuse
    #pragma unroll
    for (int mt = 0; mt < 2; ++mt) {
      #pragma unroll
      for (int reg = 0; reg < 4; ++reg)
        #pragma unroll
        for (int nt = 0; nt < 8; ++nt) {
          float v = (acc2[mt][nt][reg] + b2v[nt]) * postscale;
          unsigned short h, l;
          split_bf(v, h, l);
          EldsH[q * 4 + reg][nt * 16 + lrow] = h;
          EldsL[q * 4 + reg][nt * 16 + lrow] = l;
        }
      #pragma unroll
      for (int u = 0; u < 8; ++u) {
        int task = lane + 64 * u;   // 512: plane=task>>8, row=(task>>4)&15, seg=task&15
        int plane = task >> 8, row16 = (task >> 4) & 15, seg = task & 15;
        int t = t0 + wave * 32 + mt * 16 + row16;
        int s = seq_row(start, batch, isMetal, t);
        size_t ro = (size_t)s * 128 + seg * 8;
        unsigned short* dst = (plane ? Ol : Oh) + ro;
        const unsigned short* src = plane ? &EldsL[row16][seg * 8] : &EldsH[row16][seg * 8];
        *(short8*)dst = *(const short8*)src;
      }
    }
  }
}

// Flash attention, swapped-operand, BARRIER-FREE: grid (NB, 6), 4 waves = 4 heads,
// 32 q/block. S^T = mfma(K, Q); softmax reduce = 7 in-lane ops + 2 shfl.
// V staged PER-WAVE into a type-consistent u32 tile (dword writes AND reads).
// P single bf16; ctx emitted as SINGLE bf16 (seq order). LDS 18944 B.
// ZERO __syncthreads.
__global__ __launch_bounds__(256, 4)
void k_flash(const unsigned short* __restrict__ Qh, const unsigned short* __restrict__ Ql,
             const unsigned short* __restrict__ Kh, const unsigned short* __restrict__ Kl,
             const unsigned short* __restrict__ Vb, const int* __restrict__ start,
             unsigned short* __restrict__ Ch) {
  __shared__ unsigned VldsW[4][32][17];               // per-wave V slice (u32), 8704 B
  __shared__ alignas(16) unsigned PtH[4][32][20];     // [wave][query][key-pair] 10240 B
  const int g = blockIdx.x;
  const int tid = threadIdx.x;
  const int wv = tid >> 6;        // head
  const int lane = tid & 63;
  const int lrow = lane & 15;
  const int quad = lane >> 4;
  const int s0 = start[g];
  const int c = start[g + 1] - s0 + 1;   // slots incl. metal at 0
  const int sbase = s0 + g;
  const int hoff = wv * 32 + quad * 8;   // k-dim offset for frags

  for (int qb = 32 * blockIdx.y; qb < c; qb += 32 * gridDim.y) {
    short8 qfh[2], qfl[2];
    #pragma unroll
    for (int mt = 0; mt < 2; ++mt) {
      int qs = qb + mt * 16 + lrow; if (qs >= c) qs = 0;
      size_t off = (size_t)(sbase + qs) * 128 + hoff;
      qfh[mt] = *(const short8*)(Qh + off);
      qfl[mt] = *(const short8*)(Ql + off);
    }
    float mr[2], lr[2];
    f32x4 O[2][2];   // [mt][nt]: O^T tile, lane: query=lrow, dim=nt*16+quad*4+reg
    #pragma unroll
    for (int mt = 0; mt < 2; ++mt) {
      mr[mt] = -3.0e38f; lr[mt] = 0.f;
      O[mt][0] = (f32x4){0.f, 0.f, 0.f, 0.f};
      O[mt][1] = (f32x4){0.f, 0.f, 0.f, 0.f};
    }

    const int nch = (c + 31) >> 5;
    for (int ch = 0; ch < nch; ++ch) {
      const int kb = ch * 32;
      const bool full = (kb + 32) <= c;   // wave-uniform: tail chunk only needs masking
      // K A-frags from global (row = key = lane&15)
      short8 kfh[2], kfl[2];
      #pragma unroll
      for (int s = 0; s < 2; ++s) {
        int ks = kb + s * 16 + lrow; if (ks >= c) ks = 0;
        size_t off = (size_t)(sbase + ks) * 128 + hoff;
        kfh[s] = *(const short8*)(Kh + off);
        kfl[s] = *(const short8*)(Kl + off);
      }
      // stage this wave's V slice (32 keys x 32 dims bf16) into wave-private LDS.
      #pragma unroll
      for (int u = 0; u < 2; ++u) {
        int task = lane + 64 * u;
        int key = task >> 2, seg = task & 3;
        int ks = kb + key; if (ks >= c) ks = 0;
        uint4 v = *(const uint4*)(Vb + (size_t)(sbase + ks) * 128 + wv * 32 + seg * 8);
        unsigned* dst = &VldsW[wv][key][seg * 4];
        dst[0] = v.x; dst[1] = v.y; dst[2] = v.z; dst[3] = v.w;
      }

      // S^T = K Q^T (split-bf16, 3 MFMA per tile). sv[mt][s]: rows=keys, cols=queries
      f32x4 sv[2][2];
      #pragma unroll
      for (int mt = 0; mt < 2; ++mt)
        #pragma unroll
        for (int s = 0; s < 2; ++s) {
          f32x4 z = (f32x4){0.f, 0.f, 0.f, 0.f};
          z = __builtin_amdgcn_mfma_f32_16x16x32_bf16(kfh[s], qfh[mt], z, 0, 0, 0);
          z = __builtin_amdgcn_mfma_f32_16x16x32_bf16(kfl[s], qfh[mt], z, 0, 0, 0);
          z = __builtin_amdgcn_mfma_f32_16x16x32_bf16(kfh[s], qfl[mt], z, 0, 0, 0);
          sv[mt][s] = z;
        }

      #pragma unroll
      for (int mt = 0; mt < 2; ++mt) {
        // mask (tail chunk only) + in-lane max over 8 keys held by this lane
        if (!full) {
          #pragma unroll
          for (int s = 0; s < 2; ++s)
            #pragma unroll
            for (int r4 = 0; r4 < 4; ++r4)
              sv[mt][s][r4] = ((kb + s * 16 + quad * 4 + r4) < c) ? sv[mt][s][r4] : -3.0e38f;
        }
        float m8 = mr[mt];
        #pragma unroll
        for (int s = 0; s < 2; ++s)
          #pragma unroll
          for (int r4 = 0; r4 < 4; ++r4)
            m8 = fmaxf(m8, sv[mt][s][r4]);
        m8 = fmaxf(m8, __shfl_xor(m8, 16));
        m8 = fmaxf(m8, __shfl_xor(m8, 32));
        float al = exp2f(mr[mt] - m8);
        mr[mt] = m8;

        float p[2][4];
        float rs = 0.f;
        #pragma unroll
        for (int s = 0; s < 2; ++s)
          #pragma unroll
          for (int r4 = 0; r4 < 4; ++r4) {
            p[s][r4] = exp2f(sv[mt][s][r4] - m8);
            rs += p[s][r4];
          }
        rs += __shfl_xor(rs, 16);
        rs += __shfl_xor(rs, 32);
        lr[mt] = lr[mt] * al + rs;

        // pack + store P^T as single bf16 (wave-private; same-wave read below)
        const int Q = mt * 16 + lrow;
        #pragma unroll
        for (int s = 0; s < 2; ++s) {
          unsigned short h0 = f2bf_rne(p[s][0]);
          unsigned short h1 = f2bf_rne(p[s][1]);
          unsigned short h2 = f2bf_rne(p[s][2]);
          unsigned short h3 = f2bf_rne(p[s][3]);
          uint2 hw;
          hw.x = (unsigned)h0 | ((unsigned)h1 << 16);
          hw.y = (unsigned)h2 | ((unsigned)h3 << 16);
          *(uint2*)&PtH[wv][Q][s * 8 + quad * 2] = hw;
        }
        // O rescale
        #pragma unroll
        for (int nt = 0; nt < 2; ++nt)
          #pragma unroll
          for (int r4 = 0; r4 < 4; ++r4)
            O[mt][nt][r4] *= al;
      }

      // compiler-only fence: pin LDS write -> read program order (no runtime cost)
      asm volatile("" ::: "memory");

      // V A-frags (transposed read from wave-private u32 tile): A[dim][key]
      short8 vf[2];
      #pragma unroll
      for (int nt = 0; nt < 2; ++nt)
        #pragma unroll
        for (int jj = 0; jj < 8; ++jj) {
          unsigned w = VldsW[wv][quad * 8 + jj][nt * 8 + (lrow >> 1)];
          vf[nt][jj] = (short)((lrow & 1) ? (w >> 16) : (w & 0xffffu));
        }

      // PV: O^T += V^T P (single-bf16 P)
      #pragma unroll
      for (int mt = 0; mt < 2; ++mt) {
        short8 bh = *(const short8*)&PtH[wv][mt * 16 + lrow][quad * 4];
        #pragma unroll
        for (int nt = 0; nt < 2; ++nt)
          O[mt][nt] = __builtin_amdgcn_mfma_f32_16x16x32_bf16(vf[nt], bh, O[mt][nt], 0, 0, 0);
      }
    }

    // store ctx (single bf16, seq order). Lane: query=lrow, dims=nt*16+quad*4+r4
    #pragma unroll
    for (int mt = 0; mt < 2; ++mt) {
      int qs = qb + mt * 16 + lrow;
      if (qs < c) {
        float inv = 1.f / lr[mt];
        size_t ro = (size_t)(sbase + qs) * 128 + wv * 32 + quad * 4;
        #pragma unroll
        for (int nt = 0; nt < 2; ++nt) {
          unsigned short h0 = f2bf_rne(O[mt][nt][0] * inv);
          unsigned short h1 = f2bf_rne(O[mt][nt][1] * inv);
          unsigned short h2 = f2bf_rne(O[mt][nt][2] * inv);
          unsigned short h3 = f2bf_rne(O[mt][nt][3] * inv);
          uint2 hw;
          hw.x = (unsigned)h0 | ((unsigned)h1 << 16);
          hw.y = (unsigned)h2 | ((unsigned)h3 << 16);
          *(uint2*)&Ch[ro + nt * 16] = hw;
        }
      }
    }
  }
}

extern "C" void kernel_launch(void* const* d_in, const int* in_sizes, int n_in,
                              void* d_out, int out_size, void* d_ws, size_t ws_size,
                              hipStream_t stream) {
  const float* x       = (const float*)d_in[0];
  const float* metal_x = (const float*)d_in[1];
  const int*   batch   = (const int*)d_in[2];
  const float* Wk      = (const float*)d_in[3];
  const float* bk      = (const float*)d_in[4];
  const float* Wq      = (const float*)d_in[5];
  const float* bq      = (const float*)d_in[6];
  const float* in_w    = (const float*)d_in[7];
  const float* in_b    = (const float*)d_in[8];
  const float* out_w   = (const float*)d_in[9];
  const float* out_b   = (const float*)d_in[10];
  float* out = (float*)d_out;

  // ---- workspace layout (float offsets) ----
  // [0,528)            start (513 ints, padded)
  // [528,66576)        (free; seqmap eliminated)
  // [66576,164880)     Wh+Wl  (2 x 98304 shorts)
  // [164880, ...)      big buffers
  float* ws = (float*)d_ws;
  int* start  = (int*)d_ws;
  unsigned short* Wh = (unsigned short*)(ws + 66576);
  unsigned short* Wl = Wh + 768 * 128;
  const size_t BUF0 = 164880;
  unsigned short* Csh = (unsigned short*)(ws + BUF0);            // ctx single bf16
  unsigned short* Qsh = (unsigned short*)(ws + BUF0 + TE);
  unsigned short* Qsl = Qsh + TE;
  unsigned short* Ksh = (unsigned short*)(ws + BUF0 + 2 * TE);
  unsigned short* Ksl = Ksh + TE;
  unsigned short* Vsb = (unsigned short*)(ws + BUF0 + 3 * TE);   // bf16 only
  // peak ws = (164880 + 3.5*TE)*4 B ~= 119.0 MB (unchanged from known-good)

  k_setup<<<640, 256, 0, stream>>>(batch, start, Wq, Wk, in_w, out_w, Wh, Wl);

  const int gb = TT / 128;  // 516
  const float SCL2 = 0.17677669529663687f * 1.4426950408889634f;  // scale*log2(e)

  // One dispatch for all three projection pipelines: {x->Hq->Q, x->Hk->K, x->V}
  k_mega<<<gb * 3, 256, 0, stream>>>(
      x, metal_x, Wh, Wl, bq, bk, in_b, SCL2,
      Vsb, Qsh, Qsl, Ksh, Ksl, start, batch);

  dim3 agrid(NB, 6);
  k_flash<<<agrid, 256, 0, stream>>>(Qsh, Qsl, Ksh, Ksl, Vsb, start, Csh);

  // out = ctx@out_w^T + b (single-bf16 A and W), token order
  k_outproj<<<gb, 256, 0, stream>>>(
      Csh, start, batch, Wh + 640 * 128,
      out_b, out, out + (size_t)NN * E);
}

// Round 22
// 204.158 us; speedup vs baseline: 1.0227x; 1.0227x over previous
//
#include <hip/hip_runtime.h>

#define E   128
#define HD  32
#define NB  512
#define NN  65536
#define TT  (NB + NN)   // 66048 tokens: [0,NB) metal, [NB,TT) nodes
#define TE  ((size_t)TT * 128)

typedef __attribute__((ext_vector_type(8))) short short8;
typedef __attribute__((ext_vector_type(4))) float f32x4;

__device__ __forceinline__ const float* row_ptr(const float* base, const float* metal, int t) {
  return (t < NB) ? metal + (size_t)t * E : base + (size_t)(t - NB) * E;
}
__device__ __forceinline__ float* row_ptr_w(float* base, float* metal, int t) {
  return (t < NB) ? metal + (size_t)t * E : base + (size_t)(t - NB) * E;
}

__device__ __forceinline__ unsigned short f2bf_rne(float x) {
  unsigned u = __float_as_uint(x);
  return (unsigned short)((u + 0x7FFFu + ((u >> 16) & 1u)) >> 16);
}
__device__ __forceinline__ void split_bf(float x, unsigned short& h, unsigned short& l) {
  h = f2bf_rne(x);
  float hf = __uint_as_float(((unsigned)h) << 16);
  l = f2bf_rne(x - hf);
}

// Merged setup: blocks [0,256) compute start[]; blocks [256,640) split weights.
// Rows of W: [0,128)Wq | [128,256)Wk | [256,640)in_w | [640,768)out_w
__global__ void k_setup(const int* __restrict__ batch, int* __restrict__ start,
                        const float* __restrict__ Wq, const float* __restrict__ Wk,
                        const float* __restrict__ in_w, const float* __restrict__ out_w,
                        unsigned short* __restrict__ Wh, unsigned short* __restrict__ Wl) {
  int b = blockIdx.x;
  if (b < 256) {
    int i = b * 256 + threadIdx.x;
    int bi = batch[i];
    int bp = (i == 0) ? -1 : batch[i - 1];
    for (int g = bp + 1; g <= bi; ++g) start[g] = i;
    if (i == NN - 1)
      for (int g = bi + 1; g <= NB; ++g) start[g] = NN;
  } else {
    int idx = (b - 256) * 256 + threadIdx.x;
    int r = idx >> 7, c = idx & 127;
    float v;
    if (r < 128)      v = Wq[r * 128 + c];
    else if (r < 256) v = Wk[(r - 128) * 128 + c];
    else if (r < 640) v = in_w[(r - 256) * 128 + c];
    else              v = out_w[(r - 640) * 128 + c];
    unsigned short h, l;
    split_bf(v, h, l);
    Wh[idx] = h;
    Wl[idx] = l;
  }
}

// seq row of token t: metal g -> start[g]+g ; node i -> i + batch[i] + 1
__global__ void k_seqmap(const int* __restrict__ batch, const int* __restrict__ start,
                         int* __restrict__ seqmap) {
  int t = blockIdx.x * 256 + threadIdx.x;
  if (t >= TT) return;
  seqmap[t] = (t < NB) ? (start[t] + t) : (t - NB + batch[t - NB] + 1);
}

// out = ctx@out_w^T + b. A = single-bf16 ctx (seq order) gathered via seqmap;
// W = SINGLE bf16 (linear path; ctx is already bf16-class; round-19 measured
// this numeric config at absmax 2^-9). 1 MFMA per 16x16 tile. LDS 20480 B.
__global__ __launch_bounds__(256, 3)
void k_outproj(const unsigned short* __restrict__ Ch,
               const int* __restrict__ rowmap,
               const unsigned short* __restrict__ Wh,
               const float* __restrict__ bias,
               float* __restrict__ Cx, float* __restrict__ Cm) {
  __shared__ char smem[20480];
  unsigned short (*AshH)[40] = (unsigned short (*)[40])smem;            // 10240 B
  unsigned short (*WldsH)[40] = (unsigned short (*)[40])(smem + 10240); // 10240 B

  const int tid = threadIdx.x;
  const int wave = tid >> 6;
  const int lane = tid & 63;
  const int lrow = lane & 15;
  const int q = lane >> 4;
  const int t0 = blockIdx.x * 128;

  f32x4 acc[2][8];
  #pragma unroll
  for (int mt = 0; mt < 2; ++mt)
    #pragma unroll
    for (int nt = 0; nt < 8; ++nt) acc[mt][nt] = (f32x4){0.f, 0.f, 0.f, 0.f};

  for (int ks = 0; ks < 4; ++ks) {
    __syncthreads();
    // A staging: 512 tasks, 2 per thread (row 0..127, seg 0..3)
    #pragma unroll
    for (int u = 0; u < 2; ++u) {
      int e = tid + u * 256;        // [0,512)
      int row = e >> 2, seg = e & 3;
      size_t go = (size_t)rowmap[t0 + row] * 128 + ks * 32 + seg * 8;
      *(short8*)&AshH[row][seg * 8] = *(const short8*)(Ch + go);
    }
    // W hi slice: 512 tasks, 2 per thread
    #pragma unroll
    for (int u = 0; u < 2; ++u) {
      int e = tid + u * 256;        // [0,512)
      int j = e >> 2, seg = e & 3;
      *(short8*)&WldsH[j][seg * 8] = *(const short8*)(Wh + j * 128 + ks * 32 + seg * 8);
    }
    __syncthreads();

    short8 ah[2];
    #pragma unroll
    for (int mt = 0; mt < 2; ++mt) {
      int m = wave * 32 + mt * 16 + lrow;
      ah[mt] = *(const short8*)&AshH[m][q * 8];
    }

    #pragma unroll
    for (int nt = 0; nt < 8; ++nt) {
      int j = nt * 16 + lrow;
      short8 bh = *(const short8*)&WldsH[j][q * 8];
      #pragma unroll
      for (int mt = 0; mt < 2; ++mt)
        acc[mt][nt] = __builtin_amdgcn_mfma_f32_16x16x32_bf16(ah[mt], bh, acc[mt][nt], 0, 0, 0);
    }
  }

  #pragma unroll
  for (int mt = 0; mt < 2; ++mt) {
    #pragma unroll
    for (int reg = 0; reg < 4; ++reg) {
      int t = t0 + wave * 32 + mt * 16 + q * 4 + reg;
      float* cp = row_ptr_w(Cx, Cm, t);
      #pragma unroll
      for (int nt = 0; nt < 8; ++nt) {
        int j = nt * 16 + lrow;
        cp[j] = acc[mt][nt][reg] + bias[j];
      }
    }
  }
}

// Merged projection kernel: 3*516 blocks, group = blockIdx.x % 3.
//   group 0: x -> Hq=relu(x@Wq^T+bq) -> Q=(Hq@Wiq^T+b)*SCL2  (split-bf16 seq)
//   group 1: x -> Hk=relu(x@Wk^T+bk) -> K= Hk@Wik^T+b        (split-bf16 seq)
//   group 2: x -> V = x@Wiv^T+b                               (bf16 seq)
// UNIFORM inner loops for all groups (round-19/21 lesson: any source change in
// this kernel perturbs the fragile 96-VGPR schedule; keep EXACTLY this form).
// Epilogues drain through per-wave LDS transpose tiles for short8 global stores.
__global__ __launch_bounds__(256, 2)
void k_mega(const float* __restrict__ x, const float* __restrict__ metal_x,
            const unsigned short* __restrict__ Wh, const unsigned short* __restrict__ Wl,
            const float* __restrict__ bq, const float* __restrict__ bk,
            const float* __restrict__ in_b, float scl2,
            unsigned short* __restrict__ Voh,
            unsigned short* __restrict__ Qsh, unsigned short* __restrict__ Qsl,
            unsigned short* __restrict__ Ksh, unsigned short* __restrict__ Ksl,
            const int* __restrict__ seqmap) {
  __shared__ char smem[40960];
  // stage-1 overlay
  float (*Afl)[36] = (float (*)[36])smem;                                   // 18432 B
  unsigned short (*WldsH)[40] = (unsigned short (*)[40])(smem + 18432);     // 10240 B
  unsigned short (*WldsL)[40] = (unsigned short (*)[40])(smem + 28672);     // 10240 B
  // stage-2 overlay (separated from stage-1 by __syncthreads)
  unsigned short (*AshH)[40] = (unsigned short (*)[40])smem;
  unsigned short (*AshL)[40] = (unsigned short (*)[40])(smem + 10240);
  unsigned short (*W2ldsH)[40] = (unsigned short (*)[40])(smem + 20480);
  unsigned short (*W2ldsL)[40] = (unsigned short (*)[40])(smem + 30720);

  const int tid = threadIdx.x;
  const int wave = tid >> 6;
  const int lane = tid & 63;
  const int lrow = lane & 15;
  const int q = lane >> 4;
  const int group = (int)(blockIdx.x % 3);
  const int t0 = (int)(blockIdx.x / 3) * 128;

  // per-wave epilogue transpose tiles (reuse smem after a barrier):
  unsigned short (*EldsH)[136] = (unsigned short (*)[136])(smem + wave * 8704);
  unsigned short (*EldsL)[136] = (unsigned short (*)[136])(smem + wave * 8704 + 4352);

  // stage-1 weight: g0 Wq (rows 0), g1 Wk (rows 128), g2 in_w V-proj (rows 512)
  const int w1o = (group == 0) ? 0 : (group == 1) ? 128 * 128 : 512 * 128;
  const unsigned short* W1h = Wh + w1o;
  const unsigned short* W1l = Wl + w1o;

  f32x4 acc1[2][8];
  #pragma unroll
  for (int mt = 0; mt < 2; ++mt)
    #pragma unroll
    for (int nt = 0; nt < 8; ++nt) acc1[mt][nt] = (f32x4){0.f, 0.f, 0.f, 0.f};

  // ---- stage 1: x tile -> acc1 ----
  for (int ks = 0; ks < 4; ++ks) {
    __syncthreads();
    #pragma unroll
    for (int u = 0; u < 4; ++u) {
      int e4 = tid + u * 256;
      int m = e4 >> 3, k4 = e4 & 7;
      const float* rp = row_ptr(x, metal_x, t0 + m);
      float4 v = ((const float4*)(rp + ks * 32))[k4];
      *(float4*)&Afl[m][k4 * 4] = v;
    }
    #pragma unroll
    for (int u = 0; u < 4; ++u) {
      int idx = tid + u * 256;
      int half = idx >> 9, rem = idx & 511;
      int j = rem >> 2, seg = rem & 3;
      const unsigned short* src = (half ? W1l : W1h) + j * 128 + ks * 32 + seg * 8;
      short8 v = *(const short8*)src;
      unsigned short* dst = (half ? &WldsL[j][seg * 8] : &WldsH[j][seg * 8]);
      *(short8*)dst = v;
    }
    __syncthreads();

    short8 ah[2], al[2];
    #pragma unroll
    for (int mt = 0; mt < 2; ++mt) {
      int m = wave * 32 + mt * 16 + lrow;
      float4 f0 = *(const float4*)&Afl[m][q * 8];
      float4 f1 = *(const float4*)&Afl[m][q * 8 + 4];
      unsigned short h, l;
      split_bf(f0.x, h, l); ah[mt][0] = (short)h; al[mt][0] = (short)l;
      split_bf(f0.y, h, l); ah[mt][1] = (short)h; al[mt][1] = (short)l;
      split_bf(f0.z, h, l); ah[mt][2] = (short)h; al[mt][2] = (short)l;
      split_bf(f0.w, h, l); ah[mt][3] = (short)h; al[mt][3] = (short)l;
      split_bf(f1.x, h, l); ah[mt][4] = (short)h; al[mt][4] = (short)l;
      split_bf(f1.y, h, l); ah[mt][5] = (short)h; al[mt][5] = (short)l;
      split_bf(f1.z, h, l); ah[mt][6] = (short)h; al[mt][6] = (short)l;
      split_bf(f1.w, h, l); ah[mt][7] = (short)h; al[mt][7] = (short)l;
    }

    #pragma unroll
    for (int nt = 0; nt < 8; ++nt) {
      int j = nt * 16 + lrow;
      short8 bh = *(const short8*)&WldsH[j][q * 8];
      short8 bl = *(const short8*)&WldsL[j][q * 8];
      #pragma unroll
      for (int mt = 0; mt < 2; ++mt) {
        acc1[mt][nt] = __builtin_amdgcn_mfma_f32_16x16x32_bf16(ah[mt], bh, acc1[mt][nt], 0, 0, 0);
        acc1[mt][nt] = __builtin_amdgcn_mfma_f32_16x16x32_bf16(al[mt], bh, acc1[mt][nt], 0, 0, 0);
        acc1[mt][nt] = __builtin_amdgcn_mfma_f32_16x16x32_bf16(ah[mt], bl, acc1[mt][nt], 0, 0, 0);
      }
    }
  }

  // ---- group 2: V epilogue (bf16 seq order, LDS-transposed wide stores) ----
  if (group == 2) {
    const float* bv = in_b + 2 * E;
    float bvv[8];
    #pragma unroll
    for (int nt = 0; nt < 8; ++nt) bvv[nt] = bv[nt * 16 + lrow];
    __syncthreads();   // all waves done with stage-1 LDS before Elds reuse
    #pragma unroll
    for (int mt = 0; mt < 2; ++mt) {
      #pragma unroll
      for (int reg = 0; reg < 4; ++reg)
        #pragma unroll
        for (int nt = 0; nt < 8; ++nt)
          EldsH[q * 4 + reg][nt * 16 + lrow] = f2bf_rne(acc1[mt][nt][reg] + bvv[nt]);
      #pragma unroll
      for (int u = 0; u < 4; ++u) {
        int task = lane + 64 * u;                 // 256: row=task>>4, seg=task&15
        int row16 = task >> 4, seg = task & 15;
        int t = t0 + wave * 32 + mt * 16 + row16;
        size_t ro = (size_t)seqmap[t] * 128 + seg * 8;
        *(short8*)(Voh + ro) = *(const short8*)&EldsH[row16][seg * 8];
      }
    }
    return;
  }

  // ---- groups 0/1: stage 2 ----
  const int w2o = (group == 0) ? 256 * 128 : 384 * 128;
  const unsigned short* W2h = Wh + w2o;
  const unsigned short* W2l = Wl + w2o;
  const float* b1 = (group == 0) ? bq : bk;
  const float* b2 = (group == 0) ? in_b : in_b + 128;
  const float postscale = (group == 0) ? scl2 : 1.f;
  unsigned short* Oh = (group == 0) ? Qsh : Ksh;
  unsigned short* Ol = (group == 0) ? Qsl : Ksl;

  f32x4 acc2[2][8];
  #pragma unroll
  for (int mt = 0; mt < 2; ++mt)
    #pragma unroll
    for (int nt = 0; nt < 8; ++nt) acc2[mt][nt] = (f32x4){0.f, 0.f, 0.f, 0.f};

  float b1v[8];
  #pragma unroll
  for (int nt = 0; nt < 8; ++nt) b1v[nt] = b1[nt * 16 + lrow];

  #pragma unroll
  for (int ks2 = 0; ks2 < 4; ++ks2) {
    __syncthreads();   // previous overlay reads done (incl. stage-1 last iter)
    #pragma unroll
    for (int u = 0; u < 4; ++u) {
      int idx = tid + u * 256;
      int half = idx >> 9, rem = idx & 511;
      int j = rem >> 2, seg = rem & 3;
      const unsigned short* src = (half ? W2l : W2h) + j * 128 + ks2 * 32 + seg * 8;
      short8 v = *(const short8*)src;
      unsigned short* dst = (half ? &W2ldsL[j][seg * 8] : &W2ldsH[j][seg * 8]);
      *(short8*)dst = v;
    }
    // H k-slice: registers (C/D layout) -> LDS A-slice (split hi/lo)
    #pragma unroll
    for (int mt = 0; mt < 2; ++mt) {
      #pragma unroll
      for (int n2 = 0; n2 < 2; ++n2) {
        const int nt = ks2 * 2 + n2;
        #pragma unroll
        for (int reg = 0; reg < 4; ++reg) {
          int row = wave * 32 + mt * 16 + q * 4 + reg;
          float v = fmaxf(acc1[mt][nt][reg] + b1v[nt], 0.f);
          unsigned short h, l;
          split_bf(v, h, l);
          AshH[row][n2 * 16 + lrow] = h;
          AshL[row][n2 * 16 + lrow] = l;
        }
      }
    }
    __syncthreads();

    short8 ah[2], al[2];
    #pragma unroll
    for (int mt = 0; mt < 2; ++mt) {
      int m = wave * 32 + mt * 16 + lrow;
      ah[mt] = *(const short8*)&AshH[m][q * 8];
      al[mt] = *(const short8*)&AshL[m][q * 8];
    }
    #pragma unroll
    for (int nt = 0; nt < 8; ++nt) {
      int j = nt * 16 + lrow;
      short8 bh = *(const short8*)&W2ldsH[j][q * 8];
      short8 bl = *(const short8*)&W2ldsL[j][q * 8];
      #pragma unroll
      for (int mt = 0; mt < 2; ++mt) {
        acc2[mt][nt] = __builtin_amdgcn_mfma_f32_16x16x32_bf16(ah[mt], bh, acc2[mt][nt], 0, 0, 0);
        acc2[mt][nt] = __builtin_amdgcn_mfma_f32_16x16x32_bf16(al[mt], bh, acc2[mt][nt], 0, 0, 0);
        acc2[mt][nt] = __builtin_amdgcn_mfma_f32_16x16x32_bf16(ah[mt], bl, acc2[mt][nt], 0, 0, 0);
      }
    }
  }

  // ---- O epilogue (split-bf16, seq order, LDS-transposed wide stores) ----
  {
    float b2v[8];
    #pragma unroll
    for (int nt = 0; nt < 8; ++nt) b2v[nt] = b2[nt * 16 + lrow];
    __syncthreads();   // all waves done with stage-2 LDS before Elds reuse
    #pragma unroll
    for (int mt = 0; mt < 2; ++mt) {
      #pragma unroll
      for (int reg = 0; reg < 4; ++reg)
        #pragma unroll
        for (int nt = 0; nt < 8; ++nt) {
          float v = (acc2[mt][nt][reg] + b2v[nt]) * postscale;
          unsigned short h, l;
          split_bf(v, h, l);
          EldsH[q * 4 + reg][nt * 16 + lrow] = h;
          EldsL[q * 4 + reg][nt * 16 + lrow] = l;
        }
      #pragma unroll
      for (int u = 0; u < 8; ++u) {
        int task = lane + 64 * u;   // 512: plane=task>>8, row=(task>>4)&15, seg=task&15
        int plane = task >> 8, row16 = (task >> 4) & 15, seg = task & 15;
        int t = t0 + wave * 32 + mt * 16 + row16;
        size_t ro = (size_t)seqmap[t] * 128 + seg * 8;
        unsigned short* dst = (plane ? Ol : Oh) + ro;
        const unsigned short* src = plane ? &EldsL[row16][seg * 8] : &EldsH[row16][seg * 8];
        *(short8*)dst = *(const short8*)src;
      }
    }
  }
}

// Flash attention, swapped-operand, BARRIER-FREE: grid (NB, 6), 4 waves = 4 heads,
// 32 q/block. S^T = mfma(K, Q); softmax reduce = 7 in-lane ops + 2 shfl.
// V staged PER-WAVE into a type-consistent u32 tile (dword writes AND reads).
// P single bf16; ctx emitted as SINGLE bf16 (seq order). LDS 18944 B.
// ZERO __syncthreads.
__global__ __launch_bounds__(256, 4)
void k_flash(const unsigned short* __restrict__ Qh, const unsigned short* __restrict__ Ql,
             const unsigned short* __restrict__ Kh, const unsigned short* __restrict__ Kl,
             const unsigned short* __restrict__ Vb, const int* __restrict__ start,
             unsigned short* __restrict__ Ch) {
  __shared__ unsigned VldsW[4][32][17];               // per-wave V slice (u32), 8704 B
  __shared__ alignas(16) unsigned PtH[4][32][20];     // [wave][query][key-pair] 10240 B
  const int g = blockIdx.x;
  const int tid = threadIdx.x;
  const int wv = tid >> 6;        // head
  const int lane = tid & 63;
  const int lrow = lane & 15;
  const int quad = lane >> 4;
  const int s0 = start[g];
  const int c = start[g + 1] - s0 + 1;   // slots incl. metal at 0
  const int sbase = s0 + g;
  const int hoff = wv * 32 + quad * 8;   // k-dim offset for frags

  for (int qb = 32 * blockIdx.y; qb < c; qb += 32 * gridDim.y) {
    short8 qfh[2], qfl[2];
    #pragma unroll
    for (int mt = 0; mt < 2; ++mt) {
      int qs = qb + mt * 16 + lrow; if (qs >= c) qs = 0;
      size_t off = (size_t)(sbase + qs) * 128 + hoff;
      qfh[mt] = *(const short8*)(Qh + off);
      qfl[mt] = *(const short8*)(Ql + off);
    }
    float mr[2], lr[2];
    f32x4 O[2][2];   // [mt][nt]: O^T tile, lane: query=lrow, dim=nt*16+quad*4+reg
    #pragma unroll
    for (int mt = 0; mt < 2; ++mt) {
      mr[mt] = -3.0e38f; lr[mt] = 0.f;
      O[mt][0] = (f32x4){0.f, 0.f, 0.f, 0.f};
      O[mt][1] = (f32x4){0.f, 0.f, 0.f, 0.f};
    }

    const int nch = (c + 31) >> 5;
    for (int ch = 0; ch < nch; ++ch) {
      const int kb = ch * 32;
      const bool full = (kb + 32) <= c;   // wave-uniform: tail chunk only needs masking
      // K A-frags from global (row = key = lane&15)
      short8 kfh[2], kfl[2];
      #pragma unroll
      for (int s = 0; s < 2; ++s) {
        int ks = kb + s * 16 + lrow; if (ks >= c) ks = 0;
        size_t off = (size_t)(sbase + ks) * 128 + hoff;
        kfh[s] = *(const short8*)(Kh + off);
        kfl[s] = *(const short8*)(Kl + off);
      }
      // stage this wave's V slice (32 keys x 32 dims bf16) into wave-private LDS.
      #pragma unroll
      for (int u = 0; u < 2; ++u) {
        int task = lane + 64 * u;
        int key = task >> 2, seg = task & 3;
        int ks = kb + key; if (ks >= c) ks = 0;
        uint4 v = *(const uint4*)(Vb + (size_t)(sbase + ks) * 128 + wv * 32 + seg * 8);
        unsigned* dst = &VldsW[wv][key][seg * 4];
        dst[0] = v.x; dst[1] = v.y; dst[2] = v.z; dst[3] = v.w;
      }

      // S^T = K Q^T (split-bf16, 3 MFMA per tile). sv[mt][s]: rows=keys, cols=queries
      f32x4 sv[2][2];
      #pragma unroll
      for (int mt = 0; mt < 2; ++mt)
        #pragma unroll
        for (int s = 0; s < 2; ++s) {
          f32x4 z = (f32x4){0.f, 0.f, 0.f, 0.f};
          z = __builtin_amdgcn_mfma_f32_16x16x32_bf16(kfh[s], qfh[mt], z, 0, 0, 0);
          z = __builtin_amdgcn_mfma_f32_16x16x32_bf16(kfl[s], qfh[mt], z, 0, 0, 0);
          z = __builtin_amdgcn_mfma_f32_16x16x32_bf16(kfh[s], qfl[mt], z, 0, 0, 0);
          sv[mt][s] = z;
        }

      #pragma unroll
      for (int mt = 0; mt < 2; ++mt) {
        // mask (tail chunk only) + in-lane max over 8 keys held by this lane
        if (!full) {
          #pragma unroll
          for (int s = 0; s < 2; ++s)
            #pragma unroll
            for (int r4 = 0; r4 < 4; ++r4)
              sv[mt][s][r4] = ((kb + s * 16 + quad * 4 + r4) < c) ? sv[mt][s][r4] : -3.0e38f;
        }
        float m8 = mr[mt];
        #pragma unroll
        for (int s = 0; s < 2; ++s)
          #pragma unroll
          for (int r4 = 0; r4 < 4; ++r4)
            m8 = fmaxf(m8, sv[mt][s][r4]);
        m8 = fmaxf(m8, __shfl_xor(m8, 16));
        m8 = fmaxf(m8, __shfl_xor(m8, 32));
        float al = exp2f(mr[mt] - m8);
        mr[mt] = m8;

        float p[2][4];
        float rs = 0.f;
        #pragma unroll
        for (int s = 0; s < 2; ++s)
          #pragma unroll
          for (int r4 = 0; r4 < 4; ++r4) {
            p[s][r4] = exp2f(sv[mt][s][r4] - m8);
            rs += p[s][r4];
          }
        rs += __shfl_xor(rs, 16);
        rs += __shfl_xor(rs, 32);
        lr[mt] = lr[mt] * al + rs;

        // pack + store P^T as single bf16 (wave-private; same-wave read below)
        const int Q = mt * 16 + lrow;
        #pragma unroll
        for (int s = 0; s < 2; ++s) {
          unsigned short h0 = f2bf_rne(p[s][0]);
          unsigned short h1 = f2bf_rne(p[s][1]);
          unsigned short h2 = f2bf_rne(p[s][2]);
          unsigned short h3 = f2bf_rne(p[s][3]);
          uint2 hw;
          hw.x = (unsigned)h0 | ((unsigned)h1 << 16);
          hw.y = (unsigned)h2 | ((unsigned)h3 << 16);
          *(uint2*)&PtH[wv][Q][s * 8 + quad * 2] = hw;
        }
        // O rescale
        #pragma unroll
        for (int nt = 0; nt < 2; ++nt)
          #pragma unroll
          for (int r4 = 0; r4 < 4; ++r4)
            O[mt][nt][r4] *= al;
      }

      // compiler-only fence: pin LDS write -> read program order (no runtime cost)
      asm volatile("" ::: "memory");

      // V A-frags (transposed read from wave-private u32 tile): A[dim][key]
      short8 vf[2];
      #pragma unroll
      for (int nt = 0; nt < 2; ++nt)
        #pragma unroll
        for (int jj = 0; jj < 8; ++jj) {
          unsigned w = VldsW[wv][quad * 8 + jj][nt * 8 + (lrow >> 1)];
          vf[nt][jj] = (short)((lrow & 1) ? (w >> 16) : (w & 0xffffu));
        }

      // PV: O^T += V^T P (single-bf16 P)
      #pragma unroll
      for (int mt = 0; mt < 2; ++mt) {
        short8 bh = *(const short8*)&PtH[wv][mt * 16 + lrow][quad * 4];
        #pragma unroll
        for (int nt = 0; nt < 2; ++nt)
          O[mt][nt] = __builtin_amdgcn_mfma_f32_16x16x32_bf16(vf[nt], bh, O[mt][nt], 0, 0, 0);
      }
    }

    // store ctx (single bf16, seq order). Lane: query=lrow, dims=nt*16+quad*4+r4
    #pragma unroll
    for (int mt = 0; mt < 2; ++mt) {
      int qs = qb + mt * 16 + lrow;
      if (qs < c) {
        float inv = 1.f / lr[mt];
        size_t ro = (size_t)(sbase + qs) * 128 + wv * 32 + quad * 4;
        #pragma unroll
        for (int nt = 0; nt < 2; ++nt) {
          unsigned short h0 = f2bf_rne(O[mt][nt][0] * inv);
          unsigned short h1 = f2bf_rne(O[mt][nt][1] * inv);
          unsigned short h2 = f2bf_rne(O[mt][nt][2] * inv);
          unsigned short h3 = f2bf_rne(O[mt][nt][3] * inv);
          uint2 hw;
          hw.x = (unsigned)h0 | ((unsigned)h1 << 16);
          hw.y = (unsigned)h2 | ((unsigned)h3 << 16);
          *(uint2*)&Ch[ro + nt * 16] = hw;
        }
      }
    }
  }
}

extern "C" void kernel_launch(void* const* d_in, const int* in_sizes, int n_in,
                              void* d_out, int out_size, void* d_ws, size_t ws_size,
                              hipStream_t stream) {
  const float* x       = (const float*)d_in[0];
  const float* metal_x = (const float*)d_in[1];
  const int*   batch   = (const int*)d_in[2];
  const float* Wk      = (const float*)d_in[3];
  const float* bk      = (const float*)d_in[4];
  const float* Wq      = (const float*)d_in[5];
  const float* bq      = (const float*)d_in[6];
  const float* in_w    = (const float*)d_in[7];
  const float* in_b    = (const float*)d_in[8];
  const float* out_w   = (const float*)d_in[9];
  const float* out_b   = (const float*)d_in[10];
  float* out = (float*)d_out;

  // ---- workspace layout (float offsets) ----
  // [0,528)            start (513 ints, padded)
  // [528,66576)        seqmap (66048 ints)
  // [66576,164880)     Wh+Wl  (2 x 98304 shorts)
  // [164880, ...)      big buffers
  float* ws = (float*)d_ws;
  int* start  = (int*)d_ws;
  int* seqmap = (int*)(ws + 528);
  unsigned short* Wh = (unsigned short*)(ws + 66576);
  unsigned short* Wl = Wh + 768 * 128;
  const size_t BUF0 = 164880;
  unsigned short* Csh = (unsigned short*)(ws + BUF0);            // ctx single bf16
  unsigned short* Qsh = (unsigned short*)(ws + BUF0 + TE);
  unsigned short* Qsl = Qsh + TE;
  unsigned short* Ksh = (unsigned short*)(ws + BUF0 + 2 * TE);
  unsigned short* Ksl = Ksh + TE;
  unsigned short* Vsb = (unsigned short*)(ws + BUF0 + 3 * TE);   // bf16 only
  // peak ws = (164880 + 3.5*TE)*4 B ~= 119.0 MB (unchanged from known-good)

  k_setup<<<640, 256, 0, stream>>>(batch, start, Wq, Wk, in_w, out_w, Wh, Wl);
  k_seqmap<<<TT / 256, 256, 0, stream>>>(batch, start, seqmap);

  const int gb = TT / 128;  // 516
  const float SCL2 = 0.17677669529663687f * 1.4426950408889634f;  // scale*log2(e)

  // One dispatch for all three projection pipelines: {x->Hq->Q, x->Hk->K, x->V}
  k_mega<<<gb * 3, 256, 0, stream>>>(
      x, metal_x, Wh, Wl, bq, bk, in_b, SCL2,
      Vsb, Qsh, Qsl, Ksh, Ksl, seqmap);

  dim3 agrid(NB, 6);
  k_flash<<<agrid, 256, 0, stream>>>(Qsh, Qsl, Ksh, Ksl, Vsb, start, Csh);

  // out = ctx@out_w^T + b (single-bf16 A and W), token order
  k_outproj<<<gb, 256, 0, stream>>>(
      Csh, seqmap, Wh + 640 * 128,
      out_b, out, out + (size_t)NN * E);
}